// Round 1
// 753.116 us; speedup vs baseline: 1.0842x; 1.0842x over previous
//
#include <hip/hip_runtime.h>
#include <hip/hip_bf16.h>

// DKVMN: B=128 S=1024 IN=256 M=64 D=128 OUT=128.
// w_t = softmax(x @ (Wr K^T) + br K^T) precomputed (Mv-independent); scan is an
// elementwise affine recurrence; y = sigmoid(r@Wp+bp) deferred to post-GEMM.
// R6: fp32 inputs (the harness's actual dtype, flag==1) now run on MFMA via
//     bf16x3 split compensation (hi*hi + lo*hi + hi*lo, fp32 accum) for k1/k3;
//     k2 scan moved to 256-thread blocks (4 waves, one dg each) with the
//     recurrence rewritten as Mv = fma(Mv, 1-w*e, w*a) (1-FMA serial chain).

#define B_   128
#define S_   1024
#define IN_  256
#define M_   64
#define D_   128
#define OUT_ 128
#define TC_  4
#define TL_  (S_ / TC_)   // 256 steps per chunk
#define RC_  (B_ * TL_)   // 32768 chunk-local rows

typedef __hip_bfloat16 bf16;
typedef unsigned int uint32;
typedef __attribute__((ext_vector_type(8))) short s16x8;
typedef __attribute__((ext_vector_type(4))) float f32x4;

__device__ __forceinline__ float tof(bf16 v) { return __bfloat162float(v); }
__device__ __forceinline__ bf16  tob(float v) { return __float2bfloat16(v); }
__device__ __forceinline__ float ldf(const float* p, long i) { return p[i]; }
__device__ __forceinline__ float ldf(const bf16* p, long i)  { return tof(p[i]); }
__device__ __forceinline__ void  stf(float* p, long i, float v) { p[i] = v; }
__device__ __forceinline__ void  stf(bf16* p, long i, float v)  { p[i] = tob(v); }
__device__ __forceinline__ void  unp(uint32 u, float& lo, float& hi) {
  lo = __uint_as_float(u << 16);
  hi = __uint_as_float(u & 0xFFFF0000u);
}
__device__ __forceinline__ uint32 pk(float lo, float hi) {
  union { bf16 h; unsigned short u; } a, b;
  a.h = tob(lo); b.h = tob(hi);
  return (uint32)a.u | ((uint32)b.u << 16);
}
// split two fp32 into packed bf16 hi-words + packed bf16 residual-words
__device__ __forceinline__ void split2(float f0, float f1, uint32& h, uint32& l) {
  union { bf16 b; unsigned short u; } a0, a1;
  a0.b = tob(f0); a1.b = tob(f1);
  h = (uint32)a0.u | ((uint32)a1.u << 16);
  const float r0 = f0 - tof(a0.b);
  const float r1 = f1 - tof(a1.b);
  l = pk(r0, r1);
}

// ---------------- probe: decide fp32 (flag=1) vs bf16 (flag=0) inputs ----------------
__global__ __launch_bounds__(256) void k_probe(const uint32* __restrict__ xw,
                                               int* __restrict__ flag) {
  __shared__ int s[256];
  const int tid = threadIdx.x;
  int sc = 0;
#pragma unroll
  for (int k = 0; k < 8; ++k) {
    const uint32 u = xw[tid * 8 + k];
    const float v = __uint_as_float(u << 16);  // low 16 bits as bf16
    if (!(fabsf(v) < 4.0f)) sc++;              // catches big values AND NaN/Inf
  }
  s[tid] = sc;
  __syncthreads();
  for (int o = 128; o > 0; o >>= 1) {
    if (tid < o) s[tid] += s[tid + o];
    __syncthreads();
  }
  if (tid == 0) *flag = (s[0] > 64) ? 1 : 0;
}

// ---------------- K0: fold Wk = Wr @ K^T (256x64), bk = br @ K^T (64) ----------------
template <typename T>
__device__ void k0_body(const T* Wr, const T* br, const T* K,
                        float* Wk, float* bk) {
  const int idx = blockIdx.x * 256 + threadIdx.x;
  if (idx < IN_ * M_) {
    const int i = idx >> 6, m = idx & 63;
    float acc = 0.f;
    for (int d = 0; d < D_; ++d)
      acc = fmaf(ldf(Wr, (long)i * D_ + d), ldf(K, (long)m * D_ + d), acc);
    Wk[idx] = acc;  // idx == i*M_+m
  } else if (idx < IN_ * M_ + M_) {
    const int m = idx - IN_ * M_;
    float acc = 0.f;
    for (int d = 0; d < D_; ++d)
      acc = fmaf(ldf(br, d), ldf(K, (long)m * D_ + d), acc);
    bk[m] = acc;
  }
}

__global__ __launch_bounds__(256) void k0_fold(const void* Wr, const void* br,
                                               const void* K, float* Wk, float* bk,
                                               const int* flag) {
  if (*flag) k0_body<float>((const float*)Wr, (const float*)br, (const float*)K, Wk, bk);
  else       k0_body<bf16>((const bf16*)Wr, (const bf16*)br, (const bf16*)K, Wk, bk);
}

// ---------------- K0b: pack WcatT (192x256) and WpT (128x128) -----------------------
// WcatT rows 0..127 = Ww^T; rows 128..191 = (Wr@K^T)^T from fp32 Wk.
// flag==1: also pack bf16 residual tables (_lo) for bf16x3 compensation.
__global__ __launch_bounds__(256) void k0b_pack(const void* Ww, const void* Wp,
                                                const float* Wk, bf16* WTh, bf16* WTl,
                                                bf16* WpTh, bf16* WpTl,
                                                const int* flag) {
  const int f = *flag;
  const int idx = blockIdx.x * 256 + threadIdx.x;
  if (f) {
    const float* Wwf = (const float*)Ww;
    const float* Wpf = (const float*)Wp;
    if (idx < 192 * 256) {
      const int n = idx >> 8, k = idx & 255;
      const float v = (n < 128) ? Wwf[k * 128 + n] : Wk[k * 64 + (n - 128)];
      const bf16 h = tob(v);
      WTh[idx] = h;
      WTl[idx] = tob(v - tof(h));
    } else {
      const int j = idx - 192 * 256;
      const int n = j >> 7, k = j & 127;
      const float v = Wpf[k * 128 + n];
      const bf16 h = tob(v);
      WpTh[j] = h;
      WpTl[j] = tob(v - tof(h));
    }
  } else {
    const bf16* Wwb = (const bf16*)Ww;
    const bf16* Wpb = (const bf16*)Wp;
    if (idx < 192 * 256) {
      const int n = idx >> 8, k = idx & 255;
      WTh[idx] = (n < 128) ? Wwb[k * 128 + n] : tob(Wk[k * 64 + (n - 128)]);
    } else {
      const int j = idx - 192 * 256;
      const int n = j >> 7, k = j & 127;
      WpTh[j] = Wpb[k * 128 + n];
    }
  }
}

// ---------------- K1 (MFMA): [32768x256]@[256x192] + epilogue -----------------------
// Block = 64 rows (4 waves x 16). a-frag: lane holds x[row=l15][k=quad*8+j];
// b-frag: lane holds WcatT[n=ct*16+l15][k=quad*8+j]; D: row=quad*4+r, col=l15.
// F32: x fp32 split into bf16 hi/lo; acc += ah*bh + al*bh + ah*bl (bf16x3).
template <bool F32>
__device__ void k1_body(const void* x, const void* bw, const float* bk,
                        const bf16* __restrict__ WTh, const bf16* __restrict__ WTl,
                        uint32* __restrict__ ea_all, bf16* __restrict__ w_all,
                        int chunk) {
  const int tid = threadIdx.x;
  const int wave = tid >> 6, lane = tid & 63;
  const int l15 = lane & 15, quad = lane >> 4;
  const int b = blockIdx.x >> 2, tb = blockIdx.x & 3;
  const int t0 = tb * 64 + wave * 16;
  const long lr0 = (long)b * TL_ + t0;                     // chunk-local row base
  const long ar0 = (long)b * S_ + (long)chunk * TL_ + t0;  // absolute row base

  // load 8 a-frags (K=256)
  s16x8 afh[8], afl[8];
  if constexpr (F32) {
    const float* xr = (const float*)x + (ar0 + l15) * (long)IN_ + quad * 8;
#pragma unroll
    for (int k = 0; k < 8; ++k) {
      const float4 u0 = *(const float4*)(xr + k * 32);
      const float4 u1 = *(const float4*)(xr + k * 32 + 4);
      union { s16x8 v; uint32 u[4]; } H, L;
      split2(u0.x, u0.y, H.u[0], L.u[0]);
      split2(u0.z, u0.w, H.u[1], L.u[1]);
      split2(u1.x, u1.y, H.u[2], L.u[2]);
      split2(u1.z, u1.w, H.u[3], L.u[3]);
      afh[k] = H.v;
      afl[k] = L.v;
    }
  } else {
    const bf16* xr = (const bf16*)x + (ar0 + l15) * (long)IN_ + quad * 8;
#pragma unroll
    for (int k = 0; k < 8; ++k) afh[k] = *(const s16x8*)(xr + k * 32);
  }

  f32x4 acc[12];
#pragma unroll
  for (int ct = 0; ct < 12; ++ct) acc[ct] = (f32x4){0.f, 0.f, 0.f, 0.f};

#pragma unroll
  for (int ct = 0; ct < 12; ++ct) {
    const bf16* wph = WTh + ((ct * 16 + l15) << 8) + quad * 8;
    const bf16* wpl = WTl + ((ct * 16 + l15) << 8) + quad * 8;
#pragma unroll
    for (int k = 0; k < 8; ++k) {
      const s16x8 bh = *(const s16x8*)(wph + k * 32);
      acc[ct] = __builtin_amdgcn_mfma_f32_16x16x32_bf16(afh[k], bh, acc[ct], 0, 0, 0);
      if constexpr (F32) {
        const s16x8 bl = *(const s16x8*)(wpl + k * 32);
        acc[ct] = __builtin_amdgcn_mfma_f32_16x16x32_bf16(afl[k], bh, acc[ct], 0, 0, 0);
        acc[ct] = __builtin_amdgcn_mfma_f32_16x16x32_bf16(afh[k], bl, acc[ct], 0, 0, 0);
      }
    }
  }

  // epilogue: v tiles 0..7 -> e,a packed; score tiles 8..11 -> softmax
#pragma unroll
  for (int ct = 0; ct < 8; ++ct) {
    const int col = ct * 16 + l15;
    float bb;
    if constexpr (F32) bb = ((const float*)bw)[col];
    else               bb = tof(((const bf16*)bw)[col]);
#pragma unroll
    for (int r = 0; r < 4; ++r) {
      const float v = acc[ct][r] + bb;
      const float sg = 1.0f / (1.0f + exp2f(-1.44269504f * v));
      const float th = 1.0f - 2.0f / (exp2f(2.88539008f * v) + 1.0f);
      ea_all[(lr0 + quad * 4 + r) * D_ + col] = pk(sg, th);
    }
  }
  float bks[4];
#pragma unroll
  for (int g = 0; g < 4; ++g) bks[g] = bk[g * 16 + l15];
#pragma unroll
  for (int r = 0; r < 4; ++r) {
    float s[4];
    float mx = -1e30f;
#pragma unroll
    for (int g = 0; g < 4; ++g) {
      s[g] = acc[8 + g][r] + bks[g];
      mx = fmaxf(mx, s[g]);
    }
#pragma unroll
    for (int off = 1; off < 16; off <<= 1) mx = fmaxf(mx, __shfl_xor(mx, off, 64));
    float ex[4], sum = 0.f;
#pragma unroll
    for (int g = 0; g < 4; ++g) {
      ex[g] = exp2f(1.44269504f * (s[g] - mx));
      sum += ex[g];
    }
#pragma unroll
    for (int off = 1; off < 16; off <<= 1) sum += __shfl_xor(sum, off, 64);
    const float inv = 1.0f / sum;
    const long lr = lr0 + quad * 4 + r;
#pragma unroll
    for (int g = 0; g < 4; ++g)
      w_all[lr * M_ + g * 16 + l15] = tob(ex[g] * inv);
  }
}

__global__ __launch_bounds__(256) void k1_mfma(const void* x, const void* bw,
                                               const float* bk, const bf16* WTh,
                                               const bf16* WTl, uint32* ea_all,
                                               bf16* w_all, int chunk,
                                               const int* __restrict__ flag) {
  if (*flag) k1_body<true>(x, bw, bk, WTh, WTl, ea_all, w_all, chunk);
  else       k1_body<false>(x, bw, bk, WTh, WTl, ea_all, w_all, chunk);
}

// ---------------- K2: scan chunk. grid = B*8 x 256 threads (4 waves = 4 dg) ---------
// wave owns dg = (blk>>7)*4 + wave; lane = mg*4 + dl: mg owns m = mg*4..+4;
// d = dg*4 + dl. Batch-8 register ping-pong prefetch. Recurrence in c1/c2 form:
// Mv = fma(Mv, 1-w*e, w*a) -> serial chain is 1 FMA per step.
template <typename T>
__device__ void k2_body(const T* Mv0, const uint32* ea_all, const bf16* w_all,
                        float* MvS, T* r_out, int chunk) {
  const int tid = threadIdx.x;
  const int wave = tid >> 6, lane = tid & 63;
  const int mg = lane >> 2, dl = lane & 3;
  const int b = blockIdx.x & 127;
  const int dg = ((blockIdx.x >> 7) << 2) + wave;
  const int d = dg * 4 + dl;
  const int m0 = mg * 4;

  float Mv[4];
  if (chunk == 0) {
#pragma unroll
    for (int j = 0; j < 4; ++j)
      Mv[j] = ldf(Mv0, (long)(m0 + j) * D_ + d);
  } else {
#pragma unroll
    for (int j = 0; j < 4; ++j)
      Mv[j] = MvS[((long)b * M_ + m0 + j) * D_ + d];
  }

  const long lrbase = (long)b * TL_;
  const long arbase = (long)b * S_ + (long)chunk * TL_;
  const uint32* eap = ea_all + lrbase * D_ + d;
  const bf16* wap = w_all + lrbase * M_ + m0;

  uint32 erA[8], erB[8];
  uint2 wrA[8], wrB[8];
  float rbuf[8];
#pragma unroll
  for (int p = 0; p < 8; ++p) {
    erA[p] = eap[p * D_];
    wrA[p] = *(const uint2*)(wap + p * M_);
  }

  for (int t = 0; t < TL_; t += 16) {
    // load bank B = steps t+8..t+15 (always in range)
#pragma unroll
    for (int p = 0; p < 8; ++p) {
      const int ln = t + 8 + p;
      erB[p] = eap[(long)ln * D_];
      wrB[p] = *(const uint2*)(wap + (long)ln * M_);
    }
    // compute steps t..t+7 from bank A
#pragma unroll
    for (int p = 0; p < 8; ++p) {
      float e, a;
      unp(erA[p], e, a);
      float wv[4];
      unp(wrA[p].x, wv[0], wv[1]);
      unp(wrA[p].y, wv[2], wv[3]);
      float r = 0.f;
#pragma unroll
      for (int j = 0; j < 4; ++j) {
        const float c1 = fmaf(-wv[j], e, 1.0f);  // off-chain
        const float c2 = wv[j] * a;              // off-chain
        r = fmaf(wv[j], Mv[j], r);
        Mv[j] = fmaf(Mv[j], c1, c2);             // 1-FMA serial chain
      }
      r += __shfl_xor(r, 4, 64);
      r += __shfl_xor(r, 8, 64);
      r += __shfl_xor(r, 16, 64);
      r += __shfl_xor(r, 32, 64);
      rbuf[p] = r;
    }
    if (mg == 0) {
#pragma unroll
      for (int p = 0; p < 8; ++p)
        stf(r_out, (arbase + t + p) * D_ + d, rbuf[p]);
    }
    // load bank A = steps t+16..t+23 (clamped)
#pragma unroll
    for (int p = 0; p < 8; ++p) {
      int ln = t + 16 + p;
      ln = ln < TL_ ? ln : TL_ - 1;
      erA[p] = eap[(long)ln * D_];
      wrA[p] = *(const uint2*)(wap + (long)ln * M_);
    }
    // compute steps t+8..t+15 from bank B
#pragma unroll
    for (int p = 0; p < 8; ++p) {
      float e, a;
      unp(erB[p], e, a);
      float wv[4];
      unp(wrB[p].x, wv[0], wv[1]);
      unp(wrB[p].y, wv[2], wv[3]);
      float r = 0.f;
#pragma unroll
      for (int j = 0; j < 4; ++j) {
        const float c1 = fmaf(-wv[j], e, 1.0f);
        const float c2 = wv[j] * a;
        r = fmaf(wv[j], Mv[j], r);
        Mv[j] = fmaf(Mv[j], c1, c2);
      }
      r += __shfl_xor(r, 4, 64);
      r += __shfl_xor(r, 8, 64);
      r += __shfl_xor(r, 16, 64);
      r += __shfl_xor(r, 32, 64);
      rbuf[p] = r;
    }
    if (mg == 0) {
#pragma unroll
      for (int p = 0; p < 8; ++p)
        stf(r_out, (arbase + t + 8 + p) * D_ + d, rbuf[p]);
    }
  }
#pragma unroll
  for (int j = 0; j < 4; ++j)
    MvS[((long)b * M_ + m0 + j) * D_ + d] = Mv[j];
}

__global__ __launch_bounds__(256) void k2_scan(const void* Mv0, const uint32* ea_all,
                                               const bf16* w_all, float* MvS,
                                               void* r_out, int chunk,
                                               const int* flag) {
  if (*flag) k2_body<float>((const float*)Mv0, ea_all, w_all, MvS,
                            (float*)r_out, chunk);
  else       k2_body<bf16>((const bf16*)Mv0, ea_all, w_all, MvS,
                           (bf16*)r_out, chunk);
}

// ---------------- K3 (MFMA): y = sigmoid(r @ Wp + bp), in place ----------------------
// F32: r fp32 in d_out, split to bf16 hi/lo in-register, bf16x3 MFMA, write fp32 y
// in place. Each wave owns a disjoint 16-row tile: all reads land in registers
// before any store, so in-place is race-free.
template <bool F32>
__device__ void k3_body(const bf16* __restrict__ WpTh, const bf16* __restrict__ WpTl,
                        const void* bpv, void* iov) {
  const int tid = threadIdx.x;
  const int wave = tid >> 6, lane = tid & 63;
  const int l15 = lane & 15, quad = lane >> 4;
  const long row0 = (long)blockIdx.x * 64 + wave * 16;

  s16x8 afh[4], afl[4];
  if constexpr (F32) {
    const float* rr = (const float*)iov + (row0 + l15) * D_ + quad * 8;
#pragma unroll
    for (int k = 0; k < 4; ++k) {
      const float4 u0 = *(const float4*)(rr + k * 32);
      const float4 u1 = *(const float4*)(rr + k * 32 + 4);
      union { s16x8 v; uint32 u[4]; } H, L;
      split2(u0.x, u0.y, H.u[0], L.u[0]);
      split2(u0.z, u0.w, H.u[1], L.u[1]);
      split2(u1.x, u1.y, H.u[2], L.u[2]);
      split2(u1.z, u1.w, H.u[3], L.u[3]);
      afh[k] = H.v;
      afl[k] = L.v;
    }
  } else {
    const bf16* rr = (const bf16*)iov + (row0 + l15) * D_ + quad * 8;
#pragma unroll
    for (int k = 0; k < 4; ++k) afh[k] = *(const s16x8*)(rr + k * 32);
  }

  f32x4 acc[8];
#pragma unroll
  for (int ct = 0; ct < 8; ++ct) acc[ct] = (f32x4){0.f, 0.f, 0.f, 0.f};
#pragma unroll
  for (int ct = 0; ct < 8; ++ct) {
    const bf16* wph = WpTh + ((ct * 16 + l15) << 7) + quad * 8;
    const bf16* wpl = WpTl + ((ct * 16 + l15) << 7) + quad * 8;
#pragma unroll
    for (int k = 0; k < 4; ++k) {
      const s16x8 bh = *(const s16x8*)(wph + k * 32);
      acc[ct] = __builtin_amdgcn_mfma_f32_16x16x32_bf16(afh[k], bh, acc[ct], 0, 0, 0);
      if constexpr (F32) {
        const s16x8 bl = *(const s16x8*)(wpl + k * 32);
        acc[ct] = __builtin_amdgcn_mfma_f32_16x16x32_bf16(afl[k], bh, acc[ct], 0, 0, 0);
        acc[ct] = __builtin_amdgcn_mfma_f32_16x16x32_bf16(afh[k], bl, acc[ct], 0, 0, 0);
      }
    }
  }
#pragma unroll
  for (int ct = 0; ct < 8; ++ct) {
    const int col = ct * 16 + l15;
    float bb;
    if constexpr (F32) bb = ((const float*)bpv)[col];
    else               bb = tof(((const bf16*)bpv)[col]);
#pragma unroll
    for (int r = 0; r < 4; ++r) {
      const float y = 1.0f / (1.0f + exp2f(-1.44269504f * (acc[ct][r] + bb)));
      if constexpr (F32)
        ((float*)iov)[(row0 + quad * 4 + r) * OUT_ + col] = y;
      else
        ((bf16*)iov)[(row0 + quad * 4 + r) * OUT_ + col] = tob(y);
    }
  }
}

__global__ __launch_bounds__(256) void k3_mfma(const bf16* __restrict__ WpTh,
                                               const bf16* __restrict__ WpTl,
                                               const void* bpv, void* iov,
                                               const int* __restrict__ flag) {
  if (*flag) k3_body<true>(WpTh, WpTl, bpv, iov);
  else       k3_body<false>(WpTh, WpTl, bpv, iov);
}

extern "C" void kernel_launch(void* const* d_in, const int* in_sizes, int n_in,
                              void* d_out, int out_size, void* d_ws, size_t ws_size,
                              hipStream_t stream) {
  const void* x   = d_in[0];
  const void* mk  = d_in[1];
  const void* mv  = d_in[2];
  const void* Wr  = d_in[3];
  const void* br  = d_in[4];
  const void* Ww  = d_in[5];
  const void* bwv = d_in[6];
  const void* Wp  = d_in[7];
  const void* bp  = d_in[8];

  // ws layout (~24.3 MB): flag | Wk fp32 | bk fp32 | WTh/WTl bf16 192x256 |
  //                       WpTh/WpTl bf16 128x128 | ea u32 16MB | w bf16 4MB | MvS 4MB
  char* ws = (char*)d_ws;
  int*    flag   = (int*)ws;
  float*  Wk     = (float*)(ws + 16);
  float*  bk     = (float*)(ws + 16 + 65536);
  bf16*   WTh    = (bf16*)(ws + 65808);
  bf16*   WTl    = WTh + 192 * 256;
  bf16*   WpTh   = WTl + 192 * 256;
  bf16*   WpTl   = WpTh + 128 * 128;
  uint32* ea_all = (uint32*)(WpTl + 128 * 128);
  bf16*   w_all  = (bf16*)(ea_all + (size_t)RC_ * D_);
  float*  MvS    = (float*)(w_all + (size_t)RC_ * M_);

  k_probe<<<1, 256, 0, stream>>>((const uint32*)x, flag);
  k0_fold<<<(IN_ * M_ + M_ + 255) / 256, 256, 0, stream>>>(Wr, br, mk, Wk, bk, flag);
  k0b_pack<<<256, 256, 0, stream>>>(Ww, Wp, Wk, WTh, WTl, WpTh, WpTl, flag);
  for (int c = 0; c < TC_; ++c) {
    k1_mfma<<<RC_ / 64, 256, 0, stream>>>(x, bwv, bk, WTh, WTl, ea_all, w_all, c, flag);
    k2_scan<<<B_ * 8, 256, 0, stream>>>(mv, ea_all, w_all, MvS, d_out, c, flag);
  }
  k3_mfma<<<(B_ * S_) / 64, 256, 0, stream>>>(WpTh, WpTl, bp, d_out, flag);
}

// Round 3
// 699.654 us; speedup vs baseline: 1.1671x; 1.0764x over previous
//
#include <hip/hip_runtime.h>
#include <hip/hip_bf16.h>

// DKVMN: B=128 S=1024 IN=256 M=64 D=128 OUT=128.
// w_t = softmax(x @ (Wr K^T) + br K^T) precomputed (Mv-independent); scan is an
// elementwise affine recurrence; y = sigmoid(r@Wp+bp) deferred to post-GEMM.
// R8: chunk count chosen AT LAUNCH from ws_size (R7's fixed 84MB layout likely
//     overran the workspace -> container crash). TC = smallest of {1,2,4,8,16}
//     that fits: ea(RC*512B) + w(RC*128B) + MvS(4MB if TC>1) + 328KB fixed.
//     TC=1 -> single-dispatch k1/k2, Mv fully register-resident, no carry.
//     TC=4 -> identical structure to the R6 kernel that passed at 753us.

#define B_   128
#define S_   1024
#define IN_  256
#define M_   64
#define D_   128
#define OUT_ 128
#define NROWS_ (B_ * S_)   // 131072 rows

typedef __hip_bfloat16 bf16;
typedef unsigned int uint32;
typedef __attribute__((ext_vector_type(8))) short s16x8;
typedef __attribute__((ext_vector_type(4))) float f32x4;

__device__ __forceinline__ float tof(bf16 v) { return __bfloat162float(v); }
__device__ __forceinline__ bf16  tob(float v) { return __float2bfloat16(v); }
__device__ __forceinline__ float ldf(const float* p, long i) { return p[i]; }
__device__ __forceinline__ float ldf(const bf16* p, long i)  { return tof(p[i]); }
__device__ __forceinline__ void  stf(float* p, long i, float v) { p[i] = v; }
__device__ __forceinline__ void  stf(bf16* p, long i, float v)  { p[i] = tob(v); }
__device__ __forceinline__ void  unp(uint32 u, float& lo, float& hi) {
  lo = __uint_as_float(u << 16);
  hi = __uint_as_float(u & 0xFFFF0000u);
}
__device__ __forceinline__ uint32 pk(float lo, float hi) {
  union { bf16 h; unsigned short u; } a, b;
  a.h = tob(lo); b.h = tob(hi);
  return (uint32)a.u | ((uint32)b.u << 16);
}
// split two fp32 into packed bf16 hi-words + packed bf16 residual-words
__device__ __forceinline__ void split2(float f0, float f1, uint32& h, uint32& l) {
  union { bf16 b; unsigned short u; } a0, a1;
  a0.b = tob(f0); a1.b = tob(f1);
  h = (uint32)a0.u | ((uint32)a1.u << 16);
  const float r0 = f0 - tof(a0.b);
  const float r1 = f1 - tof(a1.b);
  l = pk(r0, r1);
}

// ---------------- probe: decide fp32 (flag=1) vs bf16 (flag=0) inputs ----------------
__global__ __launch_bounds__(256) void k_probe(const uint32* __restrict__ xw,
                                               int* __restrict__ flag) {
  __shared__ int s[256];
  const int tid = threadIdx.x;
  int sc = 0;
#pragma unroll
  for (int k = 0; k < 8; ++k) {
    const uint32 u = xw[tid * 8 + k];
    const float v = __uint_as_float(u << 16);  // low 16 bits as bf16
    if (!(fabsf(v) < 4.0f)) sc++;              // catches big values AND NaN/Inf
  }
  s[tid] = sc;
  __syncthreads();
  for (int o = 128; o > 0; o >>= 1) {
    if (tid < o) s[tid] += s[tid + o];
    __syncthreads();
  }
  if (tid == 0) *flag = (s[0] > 64) ? 1 : 0;
}

// ---------------- K0: fold Wk = Wr @ K^T (256x64), bk = br @ K^T (64) ----------------
template <typename T>
__device__ void k0_body(const T* Wr, const T* br, const T* K,
                        float* Wk, float* bk) {
  const int idx = blockIdx.x * 256 + threadIdx.x;
  if (idx < IN_ * M_) {
    const int i = idx >> 6, m = idx & 63;
    float acc = 0.f;
    for (int d = 0; d < D_; ++d)
      acc = fmaf(ldf(Wr, (long)i * D_ + d), ldf(K, (long)m * D_ + d), acc);
    Wk[idx] = acc;  // idx == i*M_+m
  } else if (idx < IN_ * M_ + M_) {
    const int m = idx - IN_ * M_;
    float acc = 0.f;
    for (int d = 0; d < D_; ++d)
      acc = fmaf(ldf(br, d), ldf(K, (long)m * D_ + d), acc);
    bk[m] = acc;
  }
}

__global__ __launch_bounds__(256) void k0_fold(const void* Wr, const void* br,
                                               const void* K, float* Wk, float* bk,
                                               const int* flag) {
  if (*flag) k0_body<float>((const float*)Wr, (const float*)br, (const float*)K, Wk, bk);
  else       k0_body<bf16>((const bf16*)Wr, (const bf16*)br, (const bf16*)K, Wk, bk);
}

// ---------------- K0b: pack WcatT (192x256) and WpT (128x128) -----------------------
// WcatT rows 0..127 = Ww^T; rows 128..191 = (Wr@K^T)^T from fp32 Wk.
// flag==1: also pack bf16 residual tables (_lo) for bf16x3 compensation.
__global__ __launch_bounds__(256) void k0b_pack(const void* Ww, const void* Wp,
                                                const float* Wk, bf16* WTh, bf16* WTl,
                                                bf16* WpTh, bf16* WpTl,
                                                const int* flag) {
  const int f = *flag;
  const int idx = blockIdx.x * 256 + threadIdx.x;
  if (f) {
    const float* Wwf = (const float*)Ww;
    const float* Wpf = (const float*)Wp;
    if (idx < 192 * 256) {
      const int n = idx >> 8, k = idx & 255;
      const float v = (n < 128) ? Wwf[k * 128 + n] : Wk[k * 64 + (n - 128)];
      const bf16 h = tob(v);
      WTh[idx] = h;
      WTl[idx] = tob(v - tof(h));
    } else {
      const int j = idx - 192 * 256;
      const int n = j >> 7, k = j & 127;
      const float v = Wpf[k * 128 + n];
      const bf16 h = tob(v);
      WpTh[j] = h;
      WpTl[j] = tob(v - tof(h));
    }
  } else {
    const bf16* Wwb = (const bf16*)Ww;
    const bf16* Wpb = (const bf16*)Wp;
    if (idx < 192 * 256) {
      const int n = idx >> 8, k = idx & 255;
      WTh[idx] = (n < 128) ? Wwb[k * 128 + n] : tob(Wk[k * 64 + (n - 128)]);
    } else {
      const int j = idx - 192 * 256;
      const int n = j >> 7, k = j & 127;
      WpTh[j] = Wpb[k * 128 + n];
    }
  }
}

// ---------------- K1 (MFMA): [RC x 256]@[256x192] + epilogue ------------------------
// Block = 64 rows (4 waves x 16). a-frag: lane holds x[row=l15][k=quad*8+j];
// b-frag: lane holds WcatT[n=ct*16+l15][k=quad*8+j]; D: row=quad*4+r, col=l15.
// F32: x fp32 split into bf16 hi/lo; acc += ah*bh + al*bh + ah*bl (bf16x3).
// tshift = log2(TL/64); chunk-local rows lr, absolute rows ar.
template <bool F32>
__device__ void k1_body(const void* x, const void* bw, const float* bk,
                        const bf16* __restrict__ WTh, const bf16* __restrict__ WTl,
                        uint32* __restrict__ ea_all, bf16* __restrict__ w_all,
                        int chunk, int TL, int tshift) {
  const int tid = threadIdx.x;
  const int wave = tid >> 6, lane = tid & 63;
  const int l15 = lane & 15, quad = lane >> 4;
  const int b = blockIdx.x >> tshift;
  const int tb = blockIdx.x & ((1 << tshift) - 1);
  const int t0 = tb * 64 + wave * 16;
  const long lr0 = (long)b * TL + t0;                     // chunk-local row base
  const long ar0 = (long)b * S_ + (long)chunk * TL + t0;  // absolute row base

  // load 8 a-frags (K=256)
  s16x8 afh[8], afl[8];
  if constexpr (F32) {
    const float* xr = (const float*)x + (ar0 + l15) * (long)IN_ + quad * 8;
#pragma unroll
    for (int k = 0; k < 8; ++k) {
      const float4 u0 = *(const float4*)(xr + k * 32);
      const float4 u1 = *(const float4*)(xr + k * 32 + 4);
      union { s16x8 v; uint32 u[4]; } H, L;
      split2(u0.x, u0.y, H.u[0], L.u[0]);
      split2(u0.z, u0.w, H.u[1], L.u[1]);
      split2(u1.x, u1.y, H.u[2], L.u[2]);
      split2(u1.z, u1.w, H.u[3], L.u[3]);
      afh[k] = H.v;
      afl[k] = L.v;
    }
  } else {
    const bf16* xr = (const bf16*)x + (ar0 + l15) * (long)IN_ + quad * 8;
#pragma unroll
    for (int k = 0; k < 8; ++k) afh[k] = *(const s16x8*)(xr + k * 32);
  }

  f32x4 acc[12];
#pragma unroll
  for (int ct = 0; ct < 12; ++ct) acc[ct] = (f32x4){0.f, 0.f, 0.f, 0.f};

#pragma unroll
  for (int ct = 0; ct < 12; ++ct) {
    const bf16* wph = WTh + ((ct * 16 + l15) << 8) + quad * 8;
    const bf16* wpl = WTl + ((ct * 16 + l15) << 8) + quad * 8;
#pragma unroll
    for (int k = 0; k < 8; ++k) {
      const s16x8 bh = *(const s16x8*)(wph + k * 32);
      acc[ct] = __builtin_amdgcn_mfma_f32_16x16x32_bf16(afh[k], bh, acc[ct], 0, 0, 0);
      if constexpr (F32) {
        const s16x8 bl = *(const s16x8*)(wpl + k * 32);
        acc[ct] = __builtin_amdgcn_mfma_f32_16x16x32_bf16(afl[k], bh, acc[ct], 0, 0, 0);
        acc[ct] = __builtin_amdgcn_mfma_f32_16x16x32_bf16(afh[k], bl, acc[ct], 0, 0, 0);
      }
    }
  }

  // epilogue: v tiles 0..7 -> e,a packed; score tiles 8..11 -> softmax
#pragma unroll
  for (int ct = 0; ct < 8; ++ct) {
    const int col = ct * 16 + l15;
    float bb;
    if constexpr (F32) bb = ((const float*)bw)[col];
    else               bb = tof(((const bf16*)bw)[col]);
#pragma unroll
    for (int r = 0; r < 4; ++r) {
      const float v = acc[ct][r] + bb;
      const float sg = 1.0f / (1.0f + exp2f(-1.44269504f * v));
      const float th = 1.0f - 2.0f / (exp2f(2.88539008f * v) + 1.0f);
      ea_all[(lr0 + quad * 4 + r) * D_ + col] = pk(sg, th);
    }
  }
  float bks[4];
#pragma unroll
  for (int g = 0; g < 4; ++g) bks[g] = bk[g * 16 + l15];
#pragma unroll
  for (int r = 0; r < 4; ++r) {
    float s[4];
    float mx = -1e30f;
#pragma unroll
    for (int g = 0; g < 4; ++g) {
      s[g] = acc[8 + g][r] + bks[g];
      mx = fmaxf(mx, s[g]);
    }
#pragma unroll
    for (int off = 1; off < 16; off <<= 1) mx = fmaxf(mx, __shfl_xor(mx, off, 64));
    float ex[4], sum = 0.f;
#pragma unroll
    for (int g = 0; g < 4; ++g) {
      ex[g] = exp2f(1.44269504f * (s[g] - mx));
      sum += ex[g];
    }
#pragma unroll
    for (int off = 1; off < 16; off <<= 1) sum += __shfl_xor(sum, off, 64);
    const float inv = 1.0f / sum;
    const long lr = lr0 + quad * 4 + r;
#pragma unroll
    for (int g = 0; g < 4; ++g)
      w_all[lr * M_ + g * 16 + l15] = tob(ex[g] * inv);
  }
}

__global__ __launch_bounds__(256) void k1_mfma(const void* x, const void* bw,
                                               const float* bk, const bf16* WTh,
                                               const bf16* WTl, uint32* ea_all,
                                               bf16* w_all, int chunk, int TL,
                                               int tshift,
                                               const int* __restrict__ flag) {
  if (*flag) k1_body<true>(x, bw, bk, WTh, WTl, ea_all, w_all, chunk, TL, tshift);
  else       k1_body<false>(x, bw, bk, WTh, WTl, ea_all, w_all, chunk, TL, tshift);
}

// ---------------- K2: scan TL steps. grid = B*8 x 256 threads (4 waves = 4 dg) ------
// wave owns dg = (blk>>7)*4 + wave; lane = mg*4 + dl: mg owns m = mg*4..+4;
// d = dg*4 + dl. Mv register-resident within a chunk; carried via MvS between
// chunks (skipped entirely when TC==1). Batch-8 register ping-pong prefetch.
// Update: Mv = fma(w, fma(-e,Mv,a), Mv).
template <typename T>
__device__ void k2_body(const T* Mv0, const uint32* ea_all, const bf16* w_all,
                        float* MvS, T* r_out, int chunk, int TL, int TC) {
  const int tid = threadIdx.x;
  const int wave = tid >> 6, lane = tid & 63;
  const int mg = lane >> 2, dl = lane & 3;
  const int b = blockIdx.x & 127;
  const int dg = ((blockIdx.x >> 7) << 2) + wave;
  const int d = dg * 4 + dl;
  const int m0 = mg * 4;

  float Mv[4];
  if (chunk == 0) {
#pragma unroll
    for (int j = 0; j < 4; ++j)
      Mv[j] = ldf(Mv0, (long)(m0 + j) * D_ + d);
  } else {
#pragma unroll
    for (int j = 0; j < 4; ++j)
      Mv[j] = MvS[((long)b * M_ + m0 + j) * D_ + d];
  }

  const long lrbase = (long)b * TL;                     // chunk-local
  const long arbase = (long)b * S_ + (long)chunk * TL;  // absolute
  const uint32* eap = ea_all + lrbase * D_ + d;
  const bf16* wap = w_all + lrbase * M_ + m0;

  uint32 erA[8], erB[8];
  uint2 wrA[8], wrB[8];
  float rbuf[8];
#pragma unroll
  for (int p = 0; p < 8; ++p) {
    erA[p] = eap[p * D_];
    wrA[p] = *(const uint2*)(wap + p * M_);
  }

  for (int t = 0; t < TL; t += 16) {
    // load bank B = steps t+8..t+15 (always in range)
#pragma unroll
    for (int p = 0; p < 8; ++p) {
      const int ln = t + 8 + p;
      erB[p] = eap[(long)ln * D_];
      wrB[p] = *(const uint2*)(wap + (long)ln * M_);
    }
    // compute steps t..t+7 from bank A
#pragma unroll
    for (int p = 0; p < 8; ++p) {
      float e, a;
      unp(erA[p], e, a);
      float wv[4];
      unp(wrA[p].x, wv[0], wv[1]);
      unp(wrA[p].y, wv[2], wv[3]);
      float r = 0.f;
#pragma unroll
      for (int j = 0; j < 4; ++j) {
        r = fmaf(wv[j], Mv[j], r);
        Mv[j] = fmaf(wv[j], fmaf(-e, Mv[j], a), Mv[j]);
      }
      r += __shfl_xor(r, 4, 64);
      r += __shfl_xor(r, 8, 64);
      r += __shfl_xor(r, 16, 64);
      r += __shfl_xor(r, 32, 64);
      rbuf[p] = r;
    }
    if (mg == 0) {
#pragma unroll
      for (int p = 0; p < 8; ++p)
        stf(r_out, (arbase + t + p) * D_ + d, rbuf[p]);
    }
    // load bank A = steps t+16..t+23 (clamped)
#pragma unroll
    for (int p = 0; p < 8; ++p) {
      int ln = t + 16 + p;
      ln = ln < TL ? ln : TL - 1;
      erA[p] = eap[(long)ln * D_];
      wrA[p] = *(const uint2*)(wap + (long)ln * M_);
    }
    // compute steps t+8..t+15 from bank B
#pragma unroll
    for (int p = 0; p < 8; ++p) {
      float e, a;
      unp(erB[p], e, a);
      float wv[4];
      unp(wrB[p].x, wv[0], wv[1]);
      unp(wrB[p].y, wv[2], wv[3]);
      float r = 0.f;
#pragma unroll
      for (int j = 0; j < 4; ++j) {
        r = fmaf(wv[j], Mv[j], r);
        Mv[j] = fmaf(wv[j], fmaf(-e, Mv[j], a), Mv[j]);
      }
      r += __shfl_xor(r, 4, 64);
      r += __shfl_xor(r, 8, 64);
      r += __shfl_xor(r, 16, 64);
      r += __shfl_xor(r, 32, 64);
      rbuf[p] = r;
    }
    if (mg == 0) {
#pragma unroll
      for (int p = 0; p < 8; ++p)
        stf(r_out, (arbase + t + 8 + p) * D_ + d, rbuf[p]);
    }
  }
  if (chunk < TC - 1) {
#pragma unroll
    for (int j = 0; j < 4; ++j)
      MvS[((long)b * M_ + m0 + j) * D_ + d] = Mv[j];
  }
}

__global__ __launch_bounds__(256) void k2_scan(const void* Mv0, const uint32* ea_all,
                                               const bf16* w_all, float* MvS,
                                               void* r_out, int chunk, int TL,
                                               int TC, const int* flag) {
  if (*flag) k2_body<float>((const float*)Mv0, ea_all, w_all, MvS,
                            (float*)r_out, chunk, TL, TC);
  else       k2_body<bf16>((const bf16*)Mv0, ea_all, w_all, MvS,
                           (bf16*)r_out, chunk, TL, TC);
}

// ---------------- K3 (MFMA): y = sigmoid(r @ Wp + bp), in place ----------------------
// F32: r fp32 in d_out, split to bf16 hi/lo in-register, bf16x3 MFMA, write fp32 y
// in place. Each wave owns a disjoint 16-row tile: all reads land in registers
// before any store, so in-place is race-free.
template <bool F32>
__device__ void k3_body(const bf16* __restrict__ WpTh, const bf16* __restrict__ WpTl,
                        const void* bpv, void* iov) {
  const int tid = threadIdx.x;
  const int wave = tid >> 6, lane = tid & 63;
  const int l15 = lane & 15, quad = lane >> 4;
  const long row0 = (long)blockIdx.x * 64 + wave * 16;

  s16x8 afh[4], afl[4];
  if constexpr (F32) {
    const float* rr = (const float*)iov + (row0 + l15) * D_ + quad * 8;
#pragma unroll
    for (int k = 0; k < 4; ++k) {
      const float4 u0 = *(const float4*)(rr + k * 32);
      const float4 u1 = *(const float4*)(rr + k * 32 + 4);
      union { s16x8 v; uint32 u[4]; } H, L;
      split2(u0.x, u0.y, H.u[0], L.u[0]);
      split2(u0.z, u0.w, H.u[1], L.u[1]);
      split2(u1.x, u1.y, H.u[2], L.u[2]);
      split2(u1.z, u1.w, H.u[3], L.u[3]);
      afh[k] = H.v;
      afl[k] = L.v;
    }
  } else {
    const bf16* rr = (const bf16*)iov + (row0 + l15) * D_ + quad * 8;
#pragma unroll
    for (int k = 0; k < 4; ++k) afh[k] = *(const s16x8*)(rr + k * 32);
  }

  f32x4 acc[8];
#pragma unroll
  for (int ct = 0; ct < 8; ++ct) acc[ct] = (f32x4){0.f, 0.f, 0.f, 0.f};
#pragma unroll
  for (int ct = 0; ct < 8; ++ct) {
    const bf16* wph = WpTh + ((ct * 16 + l15) << 7) + quad * 8;
    const bf16* wpl = WpTl + ((ct * 16 + l15) << 7) + quad * 8;
#pragma unroll
    for (int k = 0; k < 4; ++k) {
      const s16x8 bh = *(const s16x8*)(wph + k * 32);
      acc[ct] = __builtin_amdgcn_mfma_f32_16x16x32_bf16(afh[k], bh, acc[ct], 0, 0, 0);
      if constexpr (F32) {
        const s16x8 bl = *(const s16x8*)(wpl + k * 32);
        acc[ct] = __builtin_amdgcn_mfma_f32_16x16x32_bf16(afl[k], bh, acc[ct], 0, 0, 0);
        acc[ct] = __builtin_amdgcn_mfma_f32_16x16x32_bf16(afh[k], bl, acc[ct], 0, 0, 0);
      }
    }
  }
#pragma unroll
  for (int ct = 0; ct < 8; ++ct) {
    const int col = ct * 16 + l15;
    float bb;
    if constexpr (F32) bb = ((const float*)bpv)[col];
    else               bb = tof(((const bf16*)bpv)[col]);
#pragma unroll
    for (int r = 0; r < 4; ++r) {
      const float y = 1.0f / (1.0f + exp2f(-1.44269504f * (acc[ct][r] + bb)));
      if constexpr (F32)
        ((float*)iov)[(row0 + quad * 4 + r) * OUT_ + col] = y;
      else
        ((bf16*)iov)[(row0 + quad * 4 + r) * OUT_ + col] = tob(y);
    }
  }
}

__global__ __launch_bounds__(256) void k3_mfma(const bf16* __restrict__ WpTh,
                                               const bf16* __restrict__ WpTl,
                                               const void* bpv, void* iov,
                                               const int* __restrict__ flag) {
  if (*flag) k3_body<true>(WpTh, WpTl, bpv, iov);
  else       k3_body<false>(WpTh, WpTl, bpv, iov);
}

extern "C" void kernel_launch(void* const* d_in, const int* in_sizes, int n_in,
                              void* d_out, int out_size, void* d_ws, size_t ws_size,
                              hipStream_t stream) {
  const void* x   = d_in[0];
  const void* mk  = d_in[1];
  const void* mv  = d_in[2];
  const void* Wr  = d_in[3];
  const void* br  = d_in[4];
  const void* Ww  = d_in[5];
  const void* bwv = d_in[6];
  const void* Wp  = d_in[7];
  const void* bp  = d_in[8];

  // Fixed-region layout: flag | Wk fp32 | bk fp32 | WTh/WTl | WpTh/WpTl
  char* ws = (char*)d_ws;
  int*    flag = (int*)ws;
  float*  Wk   = (float*)(ws + 16);
  float*  bk   = (float*)(ws + 16 + 65536);
  bf16*   WTh  = (bf16*)(ws + 65808);
  bf16*   WTl  = WTh + 192 * 256;
  bf16*   WpTh = WTl + 192 * 256;
  bf16*   WpTl = WpTh + 128 * 128;
  char*   dyn  = (char*)(WpTl + 128 * 128);  // ws + 327,952
  const size_t fixed = (size_t)(dyn - ws);

  // Pick TC = smallest chunk count whose buffers fit ws_size.
  int TC = 16;
  for (int c = 1; c <= 16; c <<= 1) {
    const size_t rc = (size_t)NROWS_ / c;
    const size_t need = fixed + rc * (D_ * 4 + M_ * 2) +
                        (c > 1 ? (size_t)B_ * M_ * D_ * 4 : 0) + 1024;
    if (need <= ws_size) { TC = c; break; }
  }
  const int TL = S_ / TC;
  const int tshift = __builtin_ctz(TL / 64);
  const size_t RC = (size_t)NROWS_ / TC;

  uint32* ea_all = (uint32*)dyn;
  bf16*   w_all  = (bf16*)(ea_all + RC * D_);
  float*  MvS    = (float*)(w_all + RC * M_);

  k_probe<<<1, 256, 0, stream>>>((const uint32*)x, flag);
  k0_fold<<<(IN_ * M_ + M_ + 255) / 256, 256, 0, stream>>>(Wr, br, mk, Wk, bk, flag);
  k0b_pack<<<256, 256, 0, stream>>>(Ww, Wp, Wk, WTh, WTl, WpTh, WpTl, flag);
  for (int c = 0; c < TC; ++c) {
    k1_mfma<<<(int)(RC / 64), 256, 0, stream>>>(x, bwv, bk, WTh, WTl, ea_all, w_all,
                                                c, TL, tshift, flag);
    k2_scan<<<B_ * 8, 256, 0, stream>>>(mv, ea_all, w_all, MvS, d_out, c, TL, TC,
                                        flag);
  }
  k3_mfma<<<NROWS_ / 64, 256, 0, stream>>>(WpTh, WpTl, bp, d_out, flag);
}

// Round 4
// 613.116 us; speedup vs baseline: 1.3318x; 1.1411x over previous
//
#include <hip/hip_runtime.h>
#include <hip/hip_bf16.h>

// DKVMN: B=128 S=1024 IN=256 M=64 D=128 OUT=128.
// w_t = softmax(x @ (Wr K^T) + br K^T) precomputed (Mv-independent); scan is an
// elementwise affine recurrence; y = sigmoid(r@Wp+bp) deferred to post-GEMM.
// R9: k1 was latency-dead (MfmaUtil 5%, VGPR=68 -> compiler remat'd a-frags per
//     ct-tile; B-loads 16-way scattered). Fixes: (a) __launch_bounds__(256,2)
//     so afh/afl/acc stay register-resident; (b) weights packed in MFMA
//     fragment-linear order (lane-major) so every B-load is a coalesced 1KB
//     wave transaction. Same for k3. TC still chosen adaptively from ws_size.

#define B_   128
#define S_   1024
#define IN_  256
#define M_   64
#define D_   128
#define OUT_ 128
#define NROWS_ (B_ * S_)   // 131072 rows

typedef __hip_bfloat16 bf16;
typedef unsigned int uint32;
typedef __attribute__((ext_vector_type(8))) short s16x8;
typedef __attribute__((ext_vector_type(4))) float f32x4;

__device__ __forceinline__ float tof(bf16 v) { return __bfloat162float(v); }
__device__ __forceinline__ bf16  tob(float v) { return __float2bfloat16(v); }
__device__ __forceinline__ float ldf(const float* p, long i) { return p[i]; }
__device__ __forceinline__ float ldf(const bf16* p, long i)  { return tof(p[i]); }
__device__ __forceinline__ void  stf(float* p, long i, float v) { p[i] = v; }
__device__ __forceinline__ void  stf(bf16* p, long i, float v)  { p[i] = tob(v); }
__device__ __forceinline__ void  unp(uint32 u, float& lo, float& hi) {
  lo = __uint_as_float(u << 16);
  hi = __uint_as_float(u & 0xFFFF0000u);
}
__device__ __forceinline__ uint32 pk(float lo, float hi) {
  union { bf16 h; unsigned short u; } a, b;
  a.h = tob(lo); b.h = tob(hi);
  return (uint32)a.u | ((uint32)b.u << 16);
}
// split two fp32 into packed bf16 hi-words + packed bf16 residual-words
__device__ __forceinline__ void split2(float f0, float f1, uint32& h, uint32& l) {
  union { bf16 b; unsigned short u; } a0, a1;
  a0.b = tob(f0); a1.b = tob(f1);
  h = (uint32)a0.u | ((uint32)a1.u << 16);
  const float r0 = f0 - tof(a0.b);
  const float r1 = f1 - tof(a1.b);
  l = pk(r0, r1);
}

// ---------------- probe: decide fp32 (flag=1) vs bf16 (flag=0) inputs ----------------
__global__ __launch_bounds__(256) void k_probe(const uint32* __restrict__ xw,
                                               int* __restrict__ flag) {
  __shared__ int s[256];
  const int tid = threadIdx.x;
  int sc = 0;
#pragma unroll
  for (int k = 0; k < 8; ++k) {
    const uint32 u = xw[tid * 8 + k];
    const float v = __uint_as_float(u << 16);  // low 16 bits as bf16
    if (!(fabsf(v) < 4.0f)) sc++;              // catches big values AND NaN/Inf
  }
  s[tid] = sc;
  __syncthreads();
  for (int o = 128; o > 0; o >>= 1) {
    if (tid < o) s[tid] += s[tid + o];
    __syncthreads();
  }
  if (tid == 0) *flag = (s[0] > 64) ? 1 : 0;
}

// ---------------- K0: fold Wk = Wr @ K^T (256x64), bk = br @ K^T (64) ----------------
template <typename T>
__device__ void k0_body(const T* Wr, const T* br, const T* K,
                        float* Wk, float* bk) {
  const int idx = blockIdx.x * 256 + threadIdx.x;
  if (idx < IN_ * M_) {
    const int i = idx >> 6, m = idx & 63;
    float acc = 0.f;
    for (int d = 0; d < D_; ++d)
      acc = fmaf(ldf(Wr, (long)i * D_ + d), ldf(K, (long)m * D_ + d), acc);
    Wk[idx] = acc;  // idx == i*M_+m
  } else if (idx < IN_ * M_ + M_) {
    const int m = idx - IN_ * M_;
    float acc = 0.f;
    for (int d = 0; d < D_; ++d)
      acc = fmaf(ldf(br, d), ldf(K, (long)m * D_ + d), acc);
    bk[m] = acc;
  }
}

__global__ __launch_bounds__(256) void k0_fold(const void* Wr, const void* br,
                                               const void* K, float* Wk, float* bk,
                                               const int* flag) {
  if (*flag) k0_body<float>((const float*)Wr, (const float*)br, (const float*)K, Wk, bk);
  else       k0_body<bf16>((const bf16*)Wr, (const bf16*)br, (const bf16*)K, Wk, bk);
}

// ---------------- K0b: pack weights in MFMA FRAGMENT-LINEAR order -------------------
// Wcat (N=192,K=256): frag idx = ((ct*8 + kst)*64 + lane)*8 + j, lane=quad*16+l15;
//   element = Wcat[n=ct*16+l15][k=kst*32+quad*8+j], n<128 -> Ww^T, else (WrK^T)^T.
// Wp (N=128,K=128):  frag idx = ((ct*4 + kst)*64 + lane)*8 + j, same mapping.
// 49152 + 16384 = 65536 positions = grid 256x256. flag==1 also writes residuals.
__global__ __launch_bounds__(256) void k0b_pack(const void* Ww, const void* Wp,
                                                const float* Wk, bf16* WTh, bf16* WTl,
                                                bf16* WpTh, bf16* WpTl,
                                                const int* flag) {
  const int f = *flag;
  const int idx = blockIdx.x * 256 + threadIdx.x;
  if (idx < 12 * 8 * 64 * 8) {
    const int j = idx & 7, lane = (idx >> 3) & 63;
    const int kst = (idx >> 9) & 7, ct = idx >> 12;
    const int l15 = lane & 15, quad = lane >> 4;
    const int n = ct * 16 + l15;
    const int k = kst * 32 + quad * 8 + j;
    float v;
    if (f) v = (n < 128) ? ((const float*)Ww)[k * 128 + n] : Wk[k * 64 + (n - 128)];
    else   v = (n < 128) ? tof(((const bf16*)Ww)[k * 128 + n]) : Wk[k * 64 + (n - 128)];
    const bf16 h = tob(v);
    WTh[idx] = h;
    if (f) WTl[idx] = tob(v - tof(h));
  } else {
    const int o = idx - 12 * 8 * 64 * 8;
    const int j = o & 7, lane = (o >> 3) & 63;
    const int kst = (o >> 9) & 3, ct = o >> 11;
    const int l15 = lane & 15, quad = lane >> 4;
    const int n = ct * 16 + l15;
    const int k = kst * 32 + quad * 8 + j;
    float v;
    if (f) v = ((const float*)Wp)[k * 128 + n];
    else   v = tof(((const bf16*)Wp)[k * 128 + n]);
    const bf16 h = tob(v);
    WpTh[o] = h;
    if (f) WpTl[o] = tob(v - tof(h));
  }
}

// ---------------- K1 (MFMA): [RC x 256]@[256x192] + epilogue ------------------------
// Block = 64 rows (4 waves x 16). a-frag: lane holds x[row=l15][k=quad*8+j];
// b-frag loaded fragment-linear (coalesced 1KB per wave instruction).
// F32: x fp32 split into bf16 hi/lo; acc += ah*bh + al*bh + ah*bl (bf16x3).
template <bool F32>
__device__ void k1_body(const void* x, const void* bw, const float* bk,
                        const bf16* __restrict__ WTh, const bf16* __restrict__ WTl,
                        uint32* __restrict__ ea_all, bf16* __restrict__ w_all,
                        int chunk, int TL, int tshift) {
  const int tid = threadIdx.x;
  const int wave = tid >> 6, lane = tid & 63;
  const int l15 = lane & 15, quad = lane >> 4;
  const int b = blockIdx.x >> tshift;
  const int tb = blockIdx.x & ((1 << tshift) - 1);
  const int t0 = tb * 64 + wave * 16;
  const long lr0 = (long)b * TL + t0;                     // chunk-local row base
  const long ar0 = (long)b * S_ + (long)chunk * TL + t0;  // absolute row base

  // load 8 a-frags (K=256)
  s16x8 afh[8], afl[8];
  if constexpr (F32) {
    const float* xr = (const float*)x + (ar0 + l15) * (long)IN_ + quad * 8;
#pragma unroll
    for (int k = 0; k < 8; ++k) {
      const float4 u0 = *(const float4*)(xr + k * 32);
      const float4 u1 = *(const float4*)(xr + k * 32 + 4);
      union { s16x8 v; uint32 u[4]; } H, L;
      split2(u0.x, u0.y, H.u[0], L.u[0]);
      split2(u0.z, u0.w, H.u[1], L.u[1]);
      split2(u1.x, u1.y, H.u[2], L.u[2]);
      split2(u1.z, u1.w, H.u[3], L.u[3]);
      afh[k] = H.v;
      afl[k] = L.v;
    }
  } else {
    const bf16* xr = (const bf16*)x + (ar0 + l15) * (long)IN_ + quad * 8;
#pragma unroll
    for (int k = 0; k < 8; ++k) afh[k] = *(const s16x8*)(xr + k * 32);
  }

  f32x4 acc[12];
#pragma unroll
  for (int ct = 0; ct < 12; ++ct) acc[ct] = (f32x4){0.f, 0.f, 0.f, 0.f};

  // fragment-linear B: base + (ct*8+k)*512 + lane*8
  const bf16* fbh = WTh + lane * 8;
  const bf16* fbl = WTl + lane * 8;
#pragma unroll
  for (int ct = 0; ct < 12; ++ct) {
#pragma unroll
    for (int k = 0; k < 8; ++k) {
      const s16x8 bh = *(const s16x8*)(fbh + (ct * 8 + k) * 512);
      acc[ct] = __builtin_amdgcn_mfma_f32_16x16x32_bf16(afh[k], bh, acc[ct], 0, 0, 0);
      if constexpr (F32) {
        const s16x8 bl = *(const s16x8*)(fbl + (ct * 8 + k) * 512);
        acc[ct] = __builtin_amdgcn_mfma_f32_16x16x32_bf16(afl[k], bh, acc[ct], 0, 0, 0);
        acc[ct] = __builtin_amdgcn_mfma_f32_16x16x32_bf16(afh[k], bl, acc[ct], 0, 0, 0);
      }
    }
  }

  // epilogue: v tiles 0..7 -> e,a packed; score tiles 8..11 -> softmax
#pragma unroll
  for (int ct = 0; ct < 8; ++ct) {
    const int col = ct * 16 + l15;
    float bb;
    if constexpr (F32) bb = ((const float*)bw)[col];
    else               bb = tof(((const bf16*)bw)[col]);
#pragma unroll
    for (int r = 0; r < 4; ++r) {
      const float v = acc[ct][r] + bb;
      const float sg = 1.0f / (1.0f + exp2f(-1.44269504f * v));
      const float th = 1.0f - 2.0f / (exp2f(2.88539008f * v) + 1.0f);
      ea_all[(lr0 + quad * 4 + r) * D_ + col] = pk(sg, th);
    }
  }
  float bks[4];
#pragma unroll
  for (int g = 0; g < 4; ++g) bks[g] = bk[g * 16 + l15];
#pragma unroll
  for (int r = 0; r < 4; ++r) {
    float s[4];
    float mx = -1e30f;
#pragma unroll
    for (int g = 0; g < 4; ++g) {
      s[g] = acc[8 + g][r] + bks[g];
      mx = fmaxf(mx, s[g]);
    }
#pragma unroll
    for (int off = 1; off < 16; off <<= 1) mx = fmaxf(mx, __shfl_xor(mx, off, 64));
    float ex[4], sum = 0.f;
#pragma unroll
    for (int g = 0; g < 4; ++g) {
      ex[g] = exp2f(1.44269504f * (s[g] - mx));
      sum += ex[g];
    }
#pragma unroll
    for (int off = 1; off < 16; off <<= 1) sum += __shfl_xor(sum, off, 64);
    const float inv = 1.0f / sum;
    const long lr = lr0 + quad * 4 + r;
#pragma unroll
    for (int g = 0; g < 4; ++g)
      w_all[lr * M_ + g * 16 + l15] = tob(ex[g] * inv);
  }
}

__global__ __launch_bounds__(256, 2) void k1_mfma(const void* x, const void* bw,
                                                  const float* bk, const bf16* WTh,
                                                  const bf16* WTl, uint32* ea_all,
                                                  bf16* w_all, int chunk, int TL,
                                                  int tshift,
                                                  const int* __restrict__ flag) {
  if (*flag) k1_body<true>(x, bw, bk, WTh, WTl, ea_all, w_all, chunk, TL, tshift);
  else       k1_body<false>(x, bw, bk, WTh, WTl, ea_all, w_all, chunk, TL, tshift);
}

// ---------------- K2: scan TL steps. grid = B*8 x 256 threads (4 waves = 4 dg) ------
// wave owns dg = (blk>>7)*4 + wave; lane = mg*4 + dl: mg owns m = mg*4..+4;
// d = dg*4 + dl. Mv register-resident within a chunk; carried via MvS between
// chunks (skipped entirely when TC==1). Batch-8 register ping-pong prefetch.
// Update: Mv = fma(w, fma(-e,Mv,a), Mv).
template <typename T>
__device__ void k2_body(const T* Mv0, const uint32* ea_all, const bf16* w_all,
                        float* MvS, T* r_out, int chunk, int TL, int TC) {
  const int tid = threadIdx.x;
  const int wave = tid >> 6, lane = tid & 63;
  const int mg = lane >> 2, dl = lane & 3;
  const int b = blockIdx.x & 127;
  const int dg = ((blockIdx.x >> 7) << 2) + wave;
  const int d = dg * 4 + dl;
  const int m0 = mg * 4;

  float Mv[4];
  if (chunk == 0) {
#pragma unroll
    for (int j = 0; j < 4; ++j)
      Mv[j] = ldf(Mv0, (long)(m0 + j) * D_ + d);
  } else {
#pragma unroll
    for (int j = 0; j < 4; ++j)
      Mv[j] = MvS[((long)b * M_ + m0 + j) * D_ + d];
  }

  const long lrbase = (long)b * TL;                     // chunk-local
  const long arbase = (long)b * S_ + (long)chunk * TL;  // absolute
  const uint32* eap = ea_all + lrbase * D_ + d;
  const bf16* wap = w_all + lrbase * M_ + m0;

  uint32 erA[8], erB[8];
  uint2 wrA[8], wrB[8];
  float rbuf[8];
#pragma unroll
  for (int p = 0; p < 8; ++p) {
    erA[p] = eap[p * D_];
    wrA[p] = *(const uint2*)(wap + p * M_);
  }

  for (int t = 0; t < TL; t += 16) {
    // load bank B = steps t+8..t+15 (always in range)
#pragma unroll
    for (int p = 0; p < 8; ++p) {
      const int ln = t + 8 + p;
      erB[p] = eap[(long)ln * D_];
      wrB[p] = *(const uint2*)(wap + (long)ln * M_);
    }
    // compute steps t..t+7 from bank A
#pragma unroll
    for (int p = 0; p < 8; ++p) {
      float e, a;
      unp(erA[p], e, a);
      float wv[4];
      unp(wrA[p].x, wv[0], wv[1]);
      unp(wrA[p].y, wv[2], wv[3]);
      float r = 0.f;
#pragma unroll
      for (int j = 0; j < 4; ++j) {
        r = fmaf(wv[j], Mv[j], r);
        Mv[j] = fmaf(wv[j], fmaf(-e, Mv[j], a), Mv[j]);
      }
      r += __shfl_xor(r, 4, 64);
      r += __shfl_xor(r, 8, 64);
      r += __shfl_xor(r, 16, 64);
      r += __shfl_xor(r, 32, 64);
      rbuf[p] = r;
    }
    if (mg == 0) {
#pragma unroll
      for (int p = 0; p < 8; ++p)
        stf(r_out, (arbase + t + p) * D_ + d, rbuf[p]);
    }
    // load bank A = steps t+16..t+23 (clamped)
#pragma unroll
    for (int p = 0; p < 8; ++p) {
      int ln = t + 16 + p;
      ln = ln < TL ? ln : TL - 1;
      erA[p] = eap[(long)ln * D_];
      wrA[p] = *(const uint2*)(wap + (long)ln * M_);
    }
    // compute steps t+8..t+15 from bank B
#pragma unroll
    for (int p = 0; p < 8; ++p) {
      float e, a;
      unp(erB[p], e, a);
      float wv[4];
      unp(wrB[p].x, wv[0], wv[1]);
      unp(wrB[p].y, wv[2], wv[3]);
      float r = 0.f;
#pragma unroll
      for (int j = 0; j < 4; ++j) {
        r = fmaf(wv[j], Mv[j], r);
        Mv[j] = fmaf(wv[j], fmaf(-e, Mv[j], a), Mv[j]);
      }
      r += __shfl_xor(r, 4, 64);
      r += __shfl_xor(r, 8, 64);
      r += __shfl_xor(r, 16, 64);
      r += __shfl_xor(r, 32, 64);
      rbuf[p] = r;
    }
    if (mg == 0) {
#pragma unroll
      for (int p = 0; p < 8; ++p)
        stf(r_out, (arbase + t + 8 + p) * D_ + d, rbuf[p]);
    }
  }
  if (chunk < TC - 1) {
#pragma unroll
    for (int j = 0; j < 4; ++j)
      MvS[((long)b * M_ + m0 + j) * D_ + d] = Mv[j];
  }
}

__global__ __launch_bounds__(256) void k2_scan(const void* Mv0, const uint32* ea_all,
                                               const bf16* w_all, float* MvS,
                                               void* r_out, int chunk, int TL,
                                               int TC, const int* flag) {
  if (*flag) k2_body<float>((const float*)Mv0, ea_all, w_all, MvS,
                            (float*)r_out, chunk, TL, TC);
  else       k2_body<bf16>((const bf16*)Mv0, ea_all, w_all, MvS,
                           (bf16*)r_out, chunk, TL, TC);
}

// ---------------- K3 (MFMA): y = sigmoid(r @ Wp + bp), in place ----------------------
// F32: r fp32 in d_out, split to bf16 hi/lo in-register, bf16x3 MFMA, write fp32 y
// in place. Each wave owns a disjoint 16-row tile: all reads land in registers
// before any store, so in-place is race-free. B-frags fragment-linear.
template <bool F32>
__device__ void k3_body(const bf16* __restrict__ WpTh, const bf16* __restrict__ WpTl,
                        const void* bpv, void* iov) {
  const int tid = threadIdx.x;
  const int wave = tid >> 6, lane = tid & 63;
  const int l15 = lane & 15, quad = lane >> 4;
  const long row0 = (long)blockIdx.x * 64 + wave * 16;

  s16x8 afh[4], afl[4];
  if constexpr (F32) {
    const float* rr = (const float*)iov + (row0 + l15) * D_ + quad * 8;
#pragma unroll
    for (int k = 0; k < 4; ++k) {
      const float4 u0 = *(const float4*)(rr + k * 32);
      const float4 u1 = *(const float4*)(rr + k * 32 + 4);
      union { s16x8 v; uint32 u[4]; } H, L;
      split2(u0.x, u0.y, H.u[0], L.u[0]);
      split2(u0.z, u0.w, H.u[1], L.u[1]);
      split2(u1.x, u1.y, H.u[2], L.u[2]);
      split2(u1.z, u1.w, H.u[3], L.u[3]);
      afh[k] = H.v;
      afl[k] = L.v;
    }
  } else {
    const bf16* rr = (const bf16*)iov + (row0 + l15) * D_ + quad * 8;
#pragma unroll
    for (int k = 0; k < 4; ++k) afh[k] = *(const s16x8*)(rr + k * 32);
  }

  f32x4 acc[8];
#pragma unroll
  for (int ct = 0; ct < 8; ++ct) acc[ct] = (f32x4){0.f, 0.f, 0.f, 0.f};
  const bf16* fbh = WpTh + lane * 8;
  const bf16* fbl = WpTl + lane * 8;
#pragma unroll
  for (int ct = 0; ct < 8; ++ct) {
#pragma unroll
    for (int k = 0; k < 4; ++k) {
      const s16x8 bh = *(const s16x8*)(fbh + (ct * 4 + k) * 512);
      acc[ct] = __builtin_amdgcn_mfma_f32_16x16x32_bf16(afh[k], bh, acc[ct], 0, 0, 0);
      if constexpr (F32) {
        const s16x8 bl = *(const s16x8*)(fbl + (ct * 4 + k) * 512);
        acc[ct] = __builtin_amdgcn_mfma_f32_16x16x32_bf16(afl[k], bh, acc[ct], 0, 0, 0);
        acc[ct] = __builtin_amdgcn_mfma_f32_16x16x32_bf16(afh[k], bl, acc[ct], 0, 0, 0);
      }
    }
  }
#pragma unroll
  for (int ct = 0; ct < 8; ++ct) {
    const int col = ct * 16 + l15;
    float bb;
    if constexpr (F32) bb = ((const float*)bpv)[col];
    else               bb = tof(((const bf16*)bpv)[col]);
#pragma unroll
    for (int r = 0; r < 4; ++r) {
      const float y = 1.0f / (1.0f + exp2f(-1.44269504f * (acc[ct][r] + bb)));
      if constexpr (F32)
        ((float*)iov)[(row0 + quad * 4 + r) * OUT_ + col] = y;
      else
        ((bf16*)iov)[(row0 + quad * 4 + r) * OUT_ + col] = tob(y);
    }
  }
}

__global__ __launch_bounds__(256, 2) void k3_mfma(const bf16* __restrict__ WpTh,
                                                  const bf16* __restrict__ WpTl,
                                                  const void* bpv, void* iov,
                                                  const int* __restrict__ flag) {
  if (*flag) k3_body<true>(WpTh, WpTl, bpv, iov);
  else       k3_body<false>(WpTh, WpTl, bpv, iov);
}

extern "C" void kernel_launch(void* const* d_in, const int* in_sizes, int n_in,
                              void* d_out, int out_size, void* d_ws, size_t ws_size,
                              hipStream_t stream) {
  const void* x   = d_in[0];
  const void* mk  = d_in[1];
  const void* mv  = d_in[2];
  const void* Wr  = d_in[3];
  const void* br  = d_in[4];
  const void* Ww  = d_in[5];
  const void* bwv = d_in[6];
  const void* Wp  = d_in[7];
  const void* bp  = d_in[8];

  // Fixed-region layout: flag | Wk fp32 | bk fp32 | WTh/WTl | WpTh/WpTl
  char* ws = (char*)d_ws;
  int*    flag = (int*)ws;
  float*  Wk   = (float*)(ws + 16);
  float*  bk   = (float*)(ws + 16 + 65536);
  bf16*   WTh  = (bf16*)(ws + 65808);
  bf16*   WTl  = WTh + 192 * 256;
  bf16*   WpTh = WTl + 192 * 256;
  bf16*   WpTl = WpTh + 128 * 128;
  char*   dyn  = (char*)(WpTl + 128 * 128);  // ws + 327,952
  const size_t fixed = (size_t)(dyn - ws);

  // Pick TC = smallest chunk count whose buffers fit ws_size.
  int TC = 16;
  for (int c = 1; c <= 16; c <<= 1) {
    const size_t rc = (size_t)NROWS_ / c;
    const size_t need = fixed + rc * (D_ * 4 + M_ * 2) +
                        (c > 1 ? (size_t)B_ * M_ * D_ * 4 : 0) + 1024;
    if (need <= ws_size) { TC = c; break; }
  }
  const int TL = S_ / TC;
  const int tshift = __builtin_ctz(TL / 64);
  const size_t RC = (size_t)NROWS_ / TC;

  uint32* ea_all = (uint32*)dyn;
  bf16*   w_all  = (bf16*)(ea_all + RC * D_);
  float*  MvS    = (float*)(w_all + RC * M_);

  k_probe<<<1, 256, 0, stream>>>((const uint32*)x, flag);
  k0_fold<<<(IN_ * M_ + M_ + 255) / 256, 256, 0, stream>>>(Wr, br, mk, Wk, bk, flag);
  k0b_pack<<<256, 256, 0, stream>>>(Ww, Wp, Wk, WTh, WTl, WpTh, WpTl, flag);
  for (int c = 0; c < TC; ++c) {
    k1_mfma<<<(int)(RC / 64), 256, 0, stream>>>(x, bwv, bk, WTh, WTl, ea_all, w_all,
                                                c, TL, tshift, flag);
    k2_scan<<<B_ * 8, 256, 0, stream>>>(mv, ea_all, w_all, MvS, d_out, c, TL, TC,
                                        flag);
  }
  k3_mfma<<<NROWS_ / 64, 256, 0, stream>>>(WpTh, WpTl, bp, d_out, flag);
}